// Round 6
// baseline (323.780 us; speedup 1.0000x reference)
//
#include <hip/hip_runtime.h>
#include <cstdint>
#include <cstddef>

#define B_ROWS 16384
#define D_DIM  1024
#define F_REAL 1034          // real hidden/feature dim
#define N_PAD  1152          // 9 * 128
#define K_PAD  1088          // 1024 h + 10 scal + 54 zero  (17 * 64)
#define NK     (K_PAD / 64)  // 17 iterations of BK=64
#define EPSN   1e-12f

typedef __bf16 bf16x8 __attribute__((ext_vector_type(8)));
typedef float  f32x4  __attribute__((ext_vector_type(4)));
typedef unsigned short u16;

__device__ __forceinline__ u16 f2bf(float f) {
    __bf16 b = (__bf16)f;
    return __builtin_bit_cast(u16, b);
}

// -------------------------------------------------------------------------
// prep: one WAVE per row (4 rows/block). ALL loads batched up front so each
// wave keeps 12 x 1KB global loads in flight (R5 had ~2-3: VGPR_Count=28,
// VALUBusy 12.6% -> latency-bound at 1.6 TB/s).
// -------------------------------------------------------------------------
__global__ __launch_bounds__(256)
void prep_kernel(const float* __restrict__ h, const float* __restrict__ vp,
                 const float* __restrict__ vh, const float* __restrict__ nd,
                 const float* __restrict__ nsp, u16* __restrict__ A)
{
    const int row  = blockIdx.x * 4 + (threadIdx.x >> 6);
    const int lane = threadIdx.x & 63;
    const float4* hp  = (const float4*)(h  + (size_t)row * D_DIM);
    const float4* vpp = (const float4*)(vp + (size_t)row * D_DIM);
    const float4* vhp = (const float4*)(vh + (size_t)row * D_DIM);
    const float4* ndp = (const float4*)nd;
    u16* arow = A + (size_t)row * K_PAD;

    // batch-issue all global loads (independent -> 16 in flight)
    float4 pr[4], qr[4], fr[4], nr[4];
    #pragma unroll
    for (int c = 0; c < 4; ++c) pr[c] = vpp[lane + c * 64];
    #pragma unroll
    for (int c = 0; c < 4; ++c) qr[c] = vhp[lane + c * 64];
    #pragma unroll
    for (int c = 0; c < 4; ++c) fr[c] = hp[lane + c * 64];
    #pragma unroll
    for (int c = 0; c < 4; ++c) nr[c] = ndp[lane + c * 64];

    float s_pp = 0.f, s_hh = 0.f, s_pv = 0.f, s_ff = 0.f;
    float s_dd = 0.f, s_pn = 0.f, s_hn = 0.f, s_nn = 0.f;

    #pragma unroll
    for (int c = 0; c < 4; ++c) {
        float4 p = pr[c], q = qr[c], f = fr[c], n = nr[c];
        s_pp += p.x*p.x + p.y*p.y + p.z*p.z + p.w*p.w;
        s_hh += q.x*q.x + q.y*q.y + q.z*q.z + q.w*q.w;
        s_pv += p.x*q.x + p.y*q.y + p.z*q.z + p.w*q.w;
        s_ff += f.x*f.x + f.y*f.y + f.z*f.z + f.w*f.w;
        float dx = q.x-p.x, dy = q.y-p.y, dz = q.z-p.z, dw = q.w-p.w;
        s_dd += dx*dx + dy*dy + dz*dz + dw*dw;
        s_pn += p.x*n.x + p.y*n.y + p.z*n.z + p.w*n.w;
        s_hn += q.x*n.x + q.y*n.y + q.z*n.z + q.w*n.w;
        s_nn += n.x*n.x + n.y*n.y + n.z*n.z + n.w*n.w;

        ushort4 ho;
        ho.x = f2bf(f.x); ho.y = f2bf(f.y); ho.z = f2bf(f.z); ho.w = f2bf(f.w);
        *(ushort4*)(arow + (lane + c * 64) * 4) = ho;
    }

    #pragma unroll
    for (int m = 32; m >= 1; m >>= 1) {
        s_pp += __shfl_xor(s_pp, m, 64);
        s_hh += __shfl_xor(s_hh, m, 64);
        s_pv += __shfl_xor(s_pv, m, 64);
        s_ff += __shfl_xor(s_ff, m, 64);
        s_dd += __shfl_xor(s_dd, m, 64);
        s_pn += __shfl_xor(s_pn, m, 64);
        s_hn += __shfl_xor(s_hn, m, 64);
        s_nn += __shfl_xor(s_nn, m, 64);
    }

    if (lane == 0) {
        float np_ = sqrtf(s_pp), nh_ = sqrtf(s_hh), nf = sqrtf(s_ff);
        float npc = fmaxf(np_, EPSN), nhc = fmaxf(nh_, EPSN);
        float nnc = fmaxf(sqrtf(s_nn), EPSN);
        float align = s_pv / (npc * nhc);
        float ns = nsp[0];
        u16 fo[64];
        fo[0] = f2bf(align);
        fo[1] = f2bf(-align);
        fo[2] = f2bf(0.5f * (1.0f + align));      // K_O = 1
        fo[3] = f2bf(0.5f * (1.0f - align));
        fo[4] = f2bf(sqrtf(s_dd));
        fo[5] = f2bf(np_);
        fo[6] = f2bf(nh_);
        fo[7] = f2bf(nf);
        fo[8] = f2bf(ns * s_pn / (npc * nnc));
        fo[9] = f2bf(ns * s_hn / (nhc * nnc));
        #pragma unroll
        for (int i = 10; i < 64; ++i) fo[i] = 0;
        #pragma unroll
        for (int i = 0; i < 8; ++i)
            *(uint4*)(arow + D_DIM + i * 8) = *(uint4*)(fo + i * 8);
    }
}

// -------------------------------------------------------------------------
// w1 [1034x1034] f32 -> padded bf16 B^T matrix [1152 x 1088]
// -------------------------------------------------------------------------
__global__ __launch_bounds__(256)
void convw_kernel(const float* __restrict__ w1, u16* __restrict__ Bm)
{
    const int i = blockIdx.x;
    for (int j = threadIdx.x; j < K_PAD; j += 256) {
        float v = (i < F_REAL && j < F_REAL) ? w1[(size_t)i * F_REAL + j] : 0.0f;
        Bm[(size_t)i * K_PAD + j] = f2bf(v);
    }
}

// out[b*3+c] = b2[c]  (out is poisoned 0xAA each launch)
__global__ __launch_bounds__(256)
void initout_kernel(const float* __restrict__ b2, float* __restrict__ out)
{
    int i = blockIdx.x * 256 + threadIdx.x;
    if (i < B_ROWS * 3) out[i] = b2[i % 3];
}

// -------------------------------------------------------------------------
// GEMM1: 64x128 tile, BK=64, global->REG->LDS staging with LDS DOUBLE
// BUFFER -> ONE barrier per K-iter (R5 had two). bn-fastest grid so the 9
// blocks sharing an A row-block run concurrently (L2-hot staging loads).
// Fused bias+ReLU+GEMM2 epilogue -> atomic partial logits.
// -------------------------------------------------------------------------
__global__ __launch_bounds__(256)
void gemm_kernel(const u16* __restrict__ A,
                 const u16* __restrict__ Bm,
                 const float* __restrict__ b1, const float* __restrict__ w2,
                 float* __restrict__ out)
{
    // per buffer: two 32-k halves; slot layout (row*4 + (kc^(row&3)))*8
    __shared__ __bf16 As[2][2 * 64 * 32];    // 16 KB
    __shared__ __bf16 Bs[2][2 * 128 * 32];   // 32 KB

    const int tid  = threadIdx.x;
    const int lane = tid & 63;
    const int wave = tid >> 6;
    const int wm = wave >> 1, wn = wave & 1;   // wave covers 32(m) x 64(n)
    const int bn = blockIdx.x, bm = blockIdx.y;

    // per-thread staging addresses (same slot in both buffers)
    const u16* gaA;
    int slotA;
    {
        int row = tid >> 2;
        int kc  = (tid & 3) ^ (row & 3);
        gaA   = A + (size_t)(bm * 64 + row) * K_PAD + kc * 8;
        slotA = tid * 8;
    }
    const u16* gaB[2];
    int slotB[2];
    #pragma unroll
    for (int o = 0; o < 2; ++o) {
        int s   = o * 256 + tid;
        int row = s >> 2;
        int kc  = (s & 3) ^ (row & 3);
        gaB[o]   = Bm + (size_t)(bn * 128 + row) * K_PAD + kc * 8;
        slotB[o] = s * 8;
    }

    const int col  = lane & 15;   // m for A-frag, n for B-frag, n for C/D
    const int quad = lane >> 4;   // k-chunk within 32; row-quad for C/D
    const int swz  = quad ^ (col & 3);
    int aoff[2], boff[4];
    #pragma unroll
    for (int i = 0; i < 2; ++i)
        aoff[i] = ((wm * 32 + i * 16 + col) * 4 + swz) * 8;
    #pragma unroll
    for (int j = 0; j < 4; ++j)
        boff[j] = ((wn * 64 + j * 16 + col) * 4 + swz) * 8;

    f32x4 acc[2][4];
    #pragma unroll
    for (int i = 0; i < 2; ++i)
        #pragma unroll
        for (int j = 0; j < 4; ++j)
            acc[i][j] = (f32x4){0.f, 0.f, 0.f, 0.f};

    // prologue: tile 0 -> regs -> LDS buf 0
    uint4 ra0, ra1, rb00, rb01, rb10, rb11;
    ra0  = *(const uint4*)(gaA);
    ra1  = *(const uint4*)(gaA + 32);
    rb00 = *(const uint4*)(gaB[0]);
    rb01 = *(const uint4*)(gaB[0] + 32);
    rb10 = *(const uint4*)(gaB[1]);
    rb11 = *(const uint4*)(gaB[1] + 32);
    *(uint4*)(&As[0][slotA])           = ra0;
    *(uint4*)(&As[0][slotA + 2048])    = ra1;
    *(uint4*)(&Bs[0][slotB[0]])        = rb00;
    *(uint4*)(&Bs[0][slotB[0] + 4096]) = rb01;
    *(uint4*)(&Bs[0][slotB[1]])        = rb10;
    *(uint4*)(&Bs[0][slotB[1] + 4096]) = rb11;
    __syncthreads();

    for (int kt = 0; kt < NK; ++kt) {
        const int cur = kt & 1, nxt = cur ^ 1;

        // issue next-tile loads first: latency overlapped by compute below
        if (kt + 1 < NK) {
            const int ko = (kt + 1) * 64;
            ra0  = *(const uint4*)(gaA + ko);
            ra1  = *(const uint4*)(gaA + ko + 32);
            rb00 = *(const uint4*)(gaB[0] + ko);
            rb01 = *(const uint4*)(gaB[0] + ko + 32);
            rb10 = *(const uint4*)(gaB[1] + ko);
            rb11 = *(const uint4*)(gaB[1] + ko + 32);
        }

        #pragma unroll
        for (int h = 0; h < 2; ++h) {
            const __bf16* Ab = &As[cur][h * 2048];
            const __bf16* Bb = &Bs[cur][h * 4096];
            bf16x8 av[2], bv[4];
            #pragma unroll
            for (int i = 0; i < 2; ++i) av[i] = *(const bf16x8*)(Ab + aoff[i]);
            #pragma unroll
            for (int j = 0; j < 4; ++j) bv[j] = *(const bf16x8*)(Bb + boff[j]);
            #pragma unroll
            for (int i = 0; i < 2; ++i)
                #pragma unroll
                for (int j = 0; j < 4; ++j)
                    acc[i][j] = __builtin_amdgcn_mfma_f32_16x16x32_bf16(
                                    av[i], bv[j], acc[i][j], 0, 0, 0);
        }

        if (kt + 1 < NK) {
            // write into the OTHER buffer: no barrier needed before writes
            *(uint4*)(&As[nxt][slotA])           = ra0;
            *(uint4*)(&As[nxt][slotA + 2048])    = ra1;
            *(uint4*)(&Bs[nxt][slotB[0]])        = rb00;
            *(uint4*)(&Bs[nxt][slotB[0] + 4096]) = rb01;
            *(uint4*)(&Bs[nxt][slotB[1]])        = rb10;
            *(uint4*)(&Bs[nxt][slotB[1] + 4096]) = rb11;
            __syncthreads();   // reads of cur done + writes of nxt visible
        }
    }

    // epilogue: hidden = relu(acc + b1[n]); logits partial = hidden @ w2^T
    float bias[4], w20[4], w21[4], w22[4];
    #pragma unroll
    for (int ni = 0; ni < 4; ++ni) {
        int n = bn * 128 + wn * 64 + ni * 16 + col;
        bool v = n < F_REAL;   // padded rows have acc==0 anyway
        bias[ni] = v ? b1[n] : 0.0f;
        w20[ni]  = v ? w2[n] : 0.0f;
        w21[ni]  = v ? w2[F_REAL + n] : 0.0f;
        w22[ni]  = v ? w2[2 * F_REAL + n] : 0.0f;
    }
    #pragma unroll
    for (int mi = 0; mi < 2; ++mi) {
        float c0[4] = {0,0,0,0}, c1[4] = {0,0,0,0}, c2[4] = {0,0,0,0};
        #pragma unroll
        for (int ni = 0; ni < 4; ++ni) {
            #pragma unroll
            for (int r = 0; r < 4; ++r) {
                float hd = fmaxf(acc[mi][ni][r] + bias[ni], 0.0f);
                c0[r] += hd * w20[ni];
                c1[r] += hd * w21[ni];
                c2[r] += hd * w22[ni];
            }
        }
        #pragma unroll
        for (int m = 8; m >= 1; m >>= 1) {
            #pragma unroll
            for (int r = 0; r < 4; ++r) {
                c0[r] += __shfl_xor(c0[r], m, 64);
                c1[r] += __shfl_xor(c1[r], m, 64);
                c2[r] += __shfl_xor(c2[r], m, 64);
            }
        }
        if (col == 0) {
            int gm = bm * 64 + wm * 32 + mi * 16 + quad * 4;
            #pragma unroll
            for (int r = 0; r < 4; ++r) {
                atomicAdd(out + (size_t)(gm + r) * 3 + 0, c0[r]);
                atomicAdd(out + (size_t)(gm + r) * 3 + 1, c1[r]);
                atomicAdd(out + (size_t)(gm + r) * 3 + 2, c2[r]);
            }
        }
    }
}

extern "C" void kernel_launch(void* const* d_in, const int* in_sizes, int n_in,
                              void* d_out, int out_size, void* d_ws, size_t ws_size,
                              hipStream_t stream)
{
    const float* h  = (const float*)d_in[0];
    const float* vp = (const float*)d_in[1];
    const float* vh = (const float*)d_in[2];
    const float* nd = (const float*)d_in[3];
    const float* ns = (const float*)d_in[4];
    const float* w1 = (const float*)d_in[5];
    const float* b1 = (const float*)d_in[6];
    const float* w2 = (const float*)d_in[7];
    const float* b2 = (const float*)d_in[8];
    float* out = (float*)d_out;

    u16* Afull = (u16*)d_ws;                              // [16384][1088] bf16
    u16* Bfull = Afull + (size_t)B_ROWS * K_PAD;          // [1152][1088]  bf16

    prep_kernel<<<B_ROWS / 4, 256, 0, stream>>>(h, vp, vh, nd, ns, Afull);
    convw_kernel<<<N_PAD, 256, 0, stream>>>(w1, Bfull);
    initout_kernel<<<(B_ROWS * 3 + 255) / 256, 256, 0, stream>>>(b2, out);
    gemm_kernel<<<dim3(N_PAD / 128, B_ROWS / 64), 256, 0, stream>>>(
        Afull, Bfull, b1, w2, out);
}

// Round 7
// 292.121 us; speedup vs baseline: 1.1084x; 1.1084x over previous
//
#include <hip/hip_runtime.h>
#include <cstdint>
#include <cstddef>

#define B_ROWS 16384
#define D_DIM  1024
#define F_REAL 1034          // real hidden/feature dim
#define N_PAD  1152          // 9 * 128
#define K_PAD  1088          // 1024 h + 10 scal + 54 zero  (17 * 64)
#define NK     (K_PAD / 64)  // 17 iterations of BK=64
#define EPSN   1e-12f

typedef __bf16 bf16x8 __attribute__((ext_vector_type(8)));
typedef float  f32x4  __attribute__((ext_vector_type(4)));
typedef unsigned short u16;

__device__ __forceinline__ u16 f2bf(float f) {
    __bf16 b = (__bf16)f;
    return __builtin_bit_cast(u16, b);
}

// -------------------------------------------------------------------------
// prep: one WAVE per row (4 rows/block), loads batched up front.
// -------------------------------------------------------------------------
__global__ __launch_bounds__(256)
void prep_kernel(const float* __restrict__ h, const float* __restrict__ vp,
                 const float* __restrict__ vh, const float* __restrict__ nd,
                 const float* __restrict__ nsp, u16* __restrict__ A)
{
    const int row  = blockIdx.x * 4 + (threadIdx.x >> 6);
    const int lane = threadIdx.x & 63;
    const float4* hp  = (const float4*)(h  + (size_t)row * D_DIM);
    const float4* vpp = (const float4*)(vp + (size_t)row * D_DIM);
    const float4* vhp = (const float4*)(vh + (size_t)row * D_DIM);
    const float4* ndp = (const float4*)nd;
    u16* arow = A + (size_t)row * K_PAD;

    float4 pr[4], qr[4], fr[4], nr[4];
    #pragma unroll
    for (int c = 0; c < 4; ++c) pr[c] = vpp[lane + c * 64];
    #pragma unroll
    for (int c = 0; c < 4; ++c) qr[c] = vhp[lane + c * 64];
    #pragma unroll
    for (int c = 0; c < 4; ++c) fr[c] = hp[lane + c * 64];
    #pragma unroll
    for (int c = 0; c < 4; ++c) nr[c] = ndp[lane + c * 64];

    float s_pp = 0.f, s_hh = 0.f, s_pv = 0.f, s_ff = 0.f;
    float s_dd = 0.f, s_pn = 0.f, s_hn = 0.f, s_nn = 0.f;

    #pragma unroll
    for (int c = 0; c < 4; ++c) {
        float4 p = pr[c], q = qr[c], f = fr[c], n = nr[c];
        s_pp += p.x*p.x + p.y*p.y + p.z*p.z + p.w*p.w;
        s_hh += q.x*q.x + q.y*q.y + q.z*q.z + q.w*q.w;
        s_pv += p.x*q.x + p.y*q.y + p.z*q.z + p.w*q.w;
        s_ff += f.x*f.x + f.y*f.y + f.z*f.z + f.w*f.w;
        float dx = q.x-p.x, dy = q.y-p.y, dz = q.z-p.z, dw = q.w-p.w;
        s_dd += dx*dx + dy*dy + dz*dz + dw*dw;
        s_pn += p.x*n.x + p.y*n.y + p.z*n.z + p.w*n.w;
        s_hn += q.x*n.x + q.y*n.y + q.z*n.z + q.w*n.w;
        s_nn += n.x*n.x + n.y*n.y + n.z*n.z + n.w*n.w;

        ushort4 ho;
        ho.x = f2bf(f.x); ho.y = f2bf(f.y); ho.z = f2bf(f.z); ho.w = f2bf(f.w);
        *(ushort4*)(arow + (lane + c * 64) * 4) = ho;
    }

    #pragma unroll
    for (int m = 32; m >= 1; m >>= 1) {
        s_pp += __shfl_xor(s_pp, m, 64);
        s_hh += __shfl_xor(s_hh, m, 64);
        s_pv += __shfl_xor(s_pv, m, 64);
        s_ff += __shfl_xor(s_ff, m, 64);
        s_dd += __shfl_xor(s_dd, m, 64);
        s_pn += __shfl_xor(s_pn, m, 64);
        s_hn += __shfl_xor(s_hn, m, 64);
        s_nn += __shfl_xor(s_nn, m, 64);
    }

    if (lane == 0) {
        float np_ = sqrtf(s_pp), nh_ = sqrtf(s_hh), nf = sqrtf(s_ff);
        float npc = fmaxf(np_, EPSN), nhc = fmaxf(nh_, EPSN);
        float nnc = fmaxf(sqrtf(s_nn), EPSN);
        float align = s_pv / (npc * nhc);
        float ns = nsp[0];
        u16 fo[64];
        fo[0] = f2bf(align);
        fo[1] = f2bf(-align);
        fo[2] = f2bf(0.5f * (1.0f + align));      // K_O = 1
        fo[3] = f2bf(0.5f * (1.0f - align));
        fo[4] = f2bf(sqrtf(s_dd));
        fo[5] = f2bf(np_);
        fo[6] = f2bf(nh_);
        fo[7] = f2bf(nf);
        fo[8] = f2bf(ns * s_pn / (npc * nnc));
        fo[9] = f2bf(ns * s_hn / (nhc * nnc));
        #pragma unroll
        for (int i = 10; i < 64; ++i) fo[i] = 0;
        #pragma unroll
        for (int i = 0; i < 8; ++i)
            *(uint4*)(arow + D_DIM + i * 8) = *(uint4*)(fo + i * 8);
    }
}

// -------------------------------------------------------------------------
// w1 [1034x1034] f32 -> padded bf16 B^T matrix [1152 x 1088]
// -------------------------------------------------------------------------
__global__ __launch_bounds__(256)
void convw_kernel(const float* __restrict__ w1, u16* __restrict__ Bm)
{
    const int i = blockIdx.x;
    for (int j = threadIdx.x; j < K_PAD; j += 256) {
        float v = (i < F_REAL && j < F_REAL) ? w1[(size_t)i * F_REAL + j] : 0.0f;
        Bm[(size_t)i * K_PAD + j] = f2bf(v);
    }
}

// out[b*3+c] = b2[c]  (out is poisoned 0xAA each launch)
__global__ __launch_bounds__(256)
void initout_kernel(const float* __restrict__ b2, float* __restrict__ out)
{
    int i = blockIdx.x * 256 + threadIdx.x;
    if (i < B_ROWS * 3) out[i] = b2[i % 3];
}

// -------------------------------------------------------------------------
// GEMM1: 64x128 tile, BK=64, R5 2-barrier structure with DEPTH-2 register
// pipeline: loads for tile kt+2 issued at iter kt, ds_written at iter kt+1
// -> vmcnt wait covered by a full iteration (~1300cyc) instead of ~250cyc.
// Single 24KB LDS buffer, bm-fastest grid (both reverted from R6).
// Fused bias+ReLU+GEMM2 epilogue -> atomic partial logits.
// -------------------------------------------------------------------------
__global__ __launch_bounds__(256)
void gemm_kernel(const u16* __restrict__ A,
                 const u16* __restrict__ Bm,
                 const float* __restrict__ b1, const float* __restrict__ w2,
                 float* __restrict__ out)
{
    // two 32-k halves; slot layout (row*4 + (kc^(row&3)))*8
    __shared__ __bf16 As[2 * 64 * 32];    // 8 KB
    __shared__ __bf16 Bs[2 * 128 * 32];   // 16 KB

    const int tid  = threadIdx.x;
    const int lane = tid & 63;
    const int wave = tid >> 6;
    const int wm = wave >> 1, wn = wave & 1;   // wave covers 32(m) x 64(n)
    const int bm = blockIdx.x, bn = blockIdx.y;

    const u16* gaA;
    __bf16*    lA;
    {
        int row = tid >> 2;
        int kc  = (tid & 3) ^ (row & 3);
        gaA = A + (size_t)(bm * 64 + row) * K_PAD + kc * 8;
        lA  = As + tid * 8;
    }
    const u16* gaB[2];
    __bf16*    lB[2];
    #pragma unroll
    for (int o = 0; o < 2; ++o) {
        int s   = o * 256 + tid;
        int row = s >> 2;
        int kc  = (s & 3) ^ (row & 3);
        gaB[o] = Bm + (size_t)(bn * 128 + row) * K_PAD + kc * 8;
        lB[o]  = Bs + s * 8;
    }

    const int col  = lane & 15;
    const int quad = lane >> 4;
    const int swz  = quad ^ (col & 3);
    int aoff[2], boff[4];
    #pragma unroll
    for (int i = 0; i < 2; ++i)
        aoff[i] = ((wm * 32 + i * 16 + col) * 4 + swz) * 8;
    #pragma unroll
    for (int j = 0; j < 4; ++j)
        boff[j] = ((wn * 64 + j * 16 + col) * 4 + swz) * 8;

    f32x4 acc[2][4];
    #pragma unroll
    for (int i = 0; i < 2; ++i)
        #pragma unroll
        for (int j = 0; j < 4; ++j)
            acc[i][j] = (f32x4){0.f, 0.f, 0.f, 0.f};

    // two register stages; tile t lives in stage t&1
    uint4 a0_0, a1_0, b00_0, b01_0, b10_0, b11_0;
    uint4 a0_1, a1_1, b00_1, b01_1, b10_1, b11_1;

#define LOAD_STAGE(st, ko)                                                    \
    do {                                                                      \
        a0_##st  = *(const uint4*)(gaA + (ko));                               \
        a1_##st  = *(const uint4*)(gaA + (ko) + 32);                          \
        b00_##st = *(const uint4*)(gaB[0] + (ko));                            \
        b01_##st = *(const uint4*)(gaB[0] + (ko) + 32);                       \
        b10_##st = *(const uint4*)(gaB[1] + (ko));                            \
        b11_##st = *(const uint4*)(gaB[1] + (ko) + 32);                       \
    } while (0)

#define WRITE_STAGE(st)                                                       \
    do {                                                                      \
        *(uint4*)(lA)           = a0_##st;                                    \
        *(uint4*)(lA + 2048)    = a1_##st;                                    \
        *(uint4*)(lB[0])        = b00_##st;                                   \
        *(uint4*)(lB[0] + 4096) = b01_##st;                                   \
        *(uint4*)(lB[1])        = b10_##st;                                   \
        *(uint4*)(lB[1] + 4096) = b11_##st;                                   \
    } while (0)

#define COMPUTE_TILE                                                          \
    do {                                                                      \
        _Pragma("unroll")                                                     \
        for (int h = 0; h < 2; ++h) {                                         \
            const __bf16* Ab = As + h * 2048;                                 \
            const __bf16* Bb = Bs + h * 4096;                                 \
            bf16x8 av[2], bv[4];                                              \
            _Pragma("unroll")                                                 \
            for (int i = 0; i < 2; ++i) av[i] = *(const bf16x8*)(Ab + aoff[i]); \
            _Pragma("unroll")                                                 \
            for (int j = 0; j < 4; ++j) bv[j] = *(const bf16x8*)(Bb + boff[j]); \
            _Pragma("unroll")                                                 \
            for (int i = 0; i < 2; ++i)                                       \
                _Pragma("unroll")                                             \
                for (int j = 0; j < 4; ++j)                                   \
                    acc[i][j] = __builtin_amdgcn_mfma_f32_16x16x32_bf16(      \
                                    av[i], bv[j], acc[i][j], 0, 0, 0);        \
        }                                                                     \
    } while (0)

    // prologue: t0 -> S0, t1 -> S1 (both in flight), write t0, sync
    LOAD_STAGE(0, 0);
    LOAD_STAGE(1, 64);
    WRITE_STAGE(0);
    __syncthreads();

    for (int kt = 0; kt < NK; kt += 2) {
        // even sub-iter kt: prefetch t(kt+2) -> S0; write t(kt+1) from S1
        if (kt + 2 < NK) LOAD_STAGE(0, (kt + 2) * 64);
        COMPUTE_TILE;
        if (kt + 1 < NK) {
            __syncthreads();
            WRITE_STAGE(1);
            __syncthreads();

            // odd sub-iter kt+1: prefetch t(kt+3) -> S1; write t(kt+2) from S0
            if (kt + 3 < NK) LOAD_STAGE(1, (kt + 3) * 64);
            COMPUTE_TILE;
            if (kt + 2 < NK) {
                __syncthreads();
                WRITE_STAGE(0);
                __syncthreads();
            }
        }
    }

    // epilogue: hidden = relu(acc + b1[n]); logits partial = hidden @ w2^T
    float bias[4], w20[4], w21[4], w22[4];
    #pragma unroll
    for (int ni = 0; ni < 4; ++ni) {
        int n = bn * 128 + wn * 64 + ni * 16 + col;
        bool v = n < F_REAL;   // padded rows have acc==0 anyway
        bias[ni] = v ? b1[n] : 0.0f;
        w20[ni]  = v ? w2[n] : 0.0f;
        w21[ni]  = v ? w2[F_REAL + n] : 0.0f;
        w22[ni]  = v ? w2[2 * F_REAL + n] : 0.0f;
    }
    #pragma unroll
    for (int mi = 0; mi < 2; ++mi) {
        float c0[4] = {0,0,0,0}, c1[4] = {0,0,0,0}, c2[4] = {0,0,0,0};
        #pragma unroll
        for (int ni = 0; ni < 4; ++ni) {
            #pragma unroll
            for (int r = 0; r < 4; ++r) {
                float hd = fmaxf(acc[mi][ni][r] + bias[ni], 0.0f);
                c0[r] += hd * w20[ni];
                c1[r] += hd * w21[ni];
                c2[r] += hd * w22[ni];
            }
        }
        #pragma unroll
        for (int m = 8; m >= 1; m >>= 1) {
            #pragma unroll
            for (int r = 0; r < 4; ++r) {
                c0[r] += __shfl_xor(c0[r], m, 64);
                c1[r] += __shfl_xor(c1[r], m, 64);
                c2[r] += __shfl_xor(c2[r], m, 64);
            }
        }
        if (col == 0) {
            int gm = bm * 64 + wm * 32 + mi * 16 + quad * 4;
            #pragma unroll
            for (int r = 0; r < 4; ++r) {
                atomicAdd(out + (size_t)(gm + r) * 3 + 0, c0[r]);
                atomicAdd(out + (size_t)(gm + r) * 3 + 1, c1[r]);
                atomicAdd(out + (size_t)(gm + r) * 3 + 2, c2[r]);
            }
        }
    }
}

extern "C" void kernel_launch(void* const* d_in, const int* in_sizes, int n_in,
                              void* d_out, int out_size, void* d_ws, size_t ws_size,
                              hipStream_t stream)
{
    const float* h  = (const float*)d_in[0];
    const float* vp = (const float*)d_in[1];
    const float* vh = (const float*)d_in[2];
    const float* nd = (const float*)d_in[3];
    const float* ns = (const float*)d_in[4];
    const float* w1 = (const float*)d_in[5];
    const float* b1 = (const float*)d_in[6];
    const float* w2 = (const float*)d_in[7];
    const float* b2 = (const float*)d_in[8];
    float* out = (float*)d_out;

    u16* Afull = (u16*)d_ws;                              // [16384][1088] bf16
    u16* Bfull = Afull + (size_t)B_ROWS * K_PAD;          // [1152][1088]  bf16

    prep_kernel<<<B_ROWS / 4, 256, 0, stream>>>(h, vp, vh, nd, ns, Afull);
    convw_kernel<<<N_PAD, 256, 0, stream>>>(w1, Bfull);
    initout_kernel<<<(B_ROWS * 3 + 255) / 256, 256, 0, stream>>>(b2, out);
    gemm_kernel<<<dim3(B_ROWS / 64, N_PAD / 128), 256, 0, stream>>>(
        Afull, Bfull, b1, w2, out);
}